// Round 1
// baseline (661.892 us; speedup 1.0000x reference)
//
#include <hip/hip_runtime.h>

#define Bdim 8192
#define Nn 36
#define Cc 128
#define Hh 8
#define HDd 16
#define NP 40            // rows padded 36 -> 40 (4 waves x 10 rows)
#define EPSf 1e-4f

// One workgroup (256 threads = 4 waves) handles one batch b entirely in LDS.
// Phase map (LDS regions are reused):
//   sA: x            -> v
//   sB: x+pos        -> qhat
//   sC: k^3 (masked) -> attention-out
__global__ __launch_bounds__(256, 2)
void fla_fused(const float* __restrict__ x, const float* __restrict__ pos,
               const float* __restrict__ mask, const float* __restrict__ qk_w,
               const float* __restrict__ qk_b, const float* __restrict__ v_w,
               const float* __restrict__ v_b, const float* __restrict__ proj_w,
               const float* __restrict__ proj_b, const int* __restrict__ vox,
               float* __restrict__ out)
{
    __shared__ float sA[NP * Cc];
    __shared__ float sB[NP * Cc];
    __shared__ float sC[NP * Cc];
    __shared__ float sKV[Hh * 260];     // kv[h][c][d] at h*260 + c*16 + d (pad 4/h vs bank conflicts)
    __shared__ float sMask[NP];
    __shared__ float sKinv[Cc];
    __shared__ int   sVox[Nn];
    __shared__ float sInnum;

    const int t = threadIdx.x;
    const int b = blockIdx.x;
    const int lane = t & 63;
    const int wv = t >> 6;              // wave id = row group (10 rows each)

    const float* xg = x + (size_t)b * (Nn * Cc);
    const float* pg = pos + (size_t)b * (Nn * Cc);

    // ---------------- P0: stage x and x+pos (rows 36..39 zero-padded) ----------------
    #pragma unroll
    for (int it = 0; it < 5; ++it) {
        int idx = t + it * 256;          // 0..1279 over 40 rows x 32 float4
        int n = idx >> 5;
        int c4 = (idx & 31) << 2;
        float4 xv = make_float4(0.f, 0.f, 0.f, 0.f);
        float4 pv = make_float4(0.f, 0.f, 0.f, 0.f);
        if (n < Nn) {
            xv = *(const float4*)(xg + n * Cc + c4);
            pv = *(const float4*)(pg + n * Cc + c4);
        }
        *(float4*)(sA + n * Cc + c4) = xv;
        *(float4*)(sB + n * Cc + c4) =
            make_float4(xv.x + pv.x, xv.y + pv.y, xv.z + pv.z, xv.w + pv.w);
    }
    if (t < NP) sMask[t] = (t < Nn) ? mask[(size_t)b * Nn + t] : 0.f;
    if (t >= 64 && t < 64 + Nn) sVox[t - 64] = vox[(size_t)b * Nn + (t - 64)];
    __syncthreads();

    // ---------------- v GEMM: v = x @ v_w   (rows wv*10..+10, cols lane*2..+1) ------
    float accV[10][2];
    #pragma unroll
    for (int j = 0; j < 10; ++j) { accV[j][0] = 0.f; accV[j][1] = 0.f; }
    {
        const float* ap = sA + wv * 10 * Cc;
        const float* wp = v_w + lane * 2;
        #pragma unroll 2
        for (int kk = 0; kk < Cc; kk += 4) {
            float a[10][4];
            #pragma unroll
            for (int j = 0; j < 10; ++j)
                *(float4*)a[j] = *(const float4*)(ap + j * Cc + kk);   // broadcast ds_read_b128
            float w[4][2];
            #pragma unroll
            for (int i = 0; i < 4; ++i)
                *(float2*)w[i] = *(const float2*)(wp + (kk + i) * Cc); // coalesced global
            #pragma unroll
            for (int j = 0; j < 10; ++j) {
                #pragma unroll
                for (int ik = 0; ik < 4; ++ik) {
                    accV[j][0] += a[j][ik] * w[ik][0];
                    accV[j][1] += a[j][ik] * w[ik][1];
                }
            }
        }
    }

    // ---------------- qk GEMM: qk = (x+pos) @ qk_w  (cols lane*4..+3 of 256) --------
    float accQ[10][4];
    #pragma unroll
    for (int j = 0; j < 10; ++j) {
        #pragma unroll
        for (int i = 0; i < 4; ++i) accQ[j][i] = 0.f;
    }
    {
        const float* ap = sB + wv * 10 * Cc;
        const float* wp = qk_w + lane * 4;
        #pragma unroll 2
        for (int kk = 0; kk < Cc; kk += 4) {
            float a[10][4];
            #pragma unroll
            for (int j = 0; j < 10; ++j)
                *(float4*)a[j] = *(const float4*)(ap + j * Cc + kk);
            float w[4][4];
            #pragma unroll
            for (int i = 0; i < 4; ++i)
                *(float4*)w[i] = *(const float4*)(wp + (kk + i) * (2 * Cc));
            #pragma unroll
            for (int j = 0; j < 10; ++j) {
                #pragma unroll
                for (int ik = 0; ik < 4; ++ik) {
                    #pragma unroll
                    for (int col = 0; col < 4; ++col)
                        accQ[j][col] += a[j][ik] * w[ik][col];
                }
            }
        }
    }
    __syncthreads();   // all reads of sA (x) and sB (x+pos) complete

    // ---------------- write v (+bias) into sA ---------------------------------------
    {
        float vb0 = v_b[lane * 2], vb1 = v_b[lane * 2 + 1];
        #pragma unroll
        for (int j = 0; j < 10; ++j) {
            int n = wv * 10 + j;
            *(float2*)(sA + n * Cc + lane * 2) =
                make_float2(accV[j][0] + vb0, accV[j][1] + vb1);
        }
    }
    // ---------------- q: +bias, cube, row-head norm -> qhat into sB ------------------
    //                  k: +bias, *mask, cube -> k3 into sC
    if (lane < 32) {
        const int c0 = lane * 4;                    // q col group; head = lane>>2
        float bq[4]; *(float4*)bq = *(const float4*)(qk_b + c0);
        #pragma unroll
        for (int j = 0; j < 10; ++j) {
            int n = wv * 10 + j;
            float qv[4];
            #pragma unroll
            for (int i2 = 0; i2 < 4; ++i2) {
                float q1 = accQ[j][i2] + bq[i2];
                qv[i2] = q1 * q1 * q1;
            }
            float s2 = qv[0]*qv[0] + qv[1]*qv[1] + qv[2]*qv[2] + qv[3]*qv[3];
            s2 += __shfl_xor(s2, 1);                 // reduce over the 4-lane head group
            s2 += __shfl_xor(s2, 2);                 // -> sum over 16 HD elements
            float inv = 1.0f / (EPSf + sqrtf(s2));
            *(float4*)(sB + n * Cc + c0) =
                make_float4(qv[0]*inv, qv[1]*inv, qv[2]*inv, qv[3]*inv);
        }
    } else {
        const int c0 = (lane - 32) * 4;             // k col group
        float bk[4]; *(float4*)bk = *(const float4*)(qk_b + Cc + c0);
        #pragma unroll
        for (int j = 0; j < 10; ++j) {
            int n = wv * 10 + j;
            float m = sMask[n];                     // 0 for padded rows -> k3 = 0
            float kv4[4];
            #pragma unroll
            for (int i2 = 0; i2 < 4; ++i2) {
                float k1 = (accQ[j][i2] + bk[i2]) * m;
                kv4[i2] = k1 * k1 * k1;
            }
            *(float4*)(sC + n * Cc + c0) = *(float4*)kv4;
        }
    }
    __syncthreads();

    // ---------------- k column norms (over N) + 1/(sum(mask)+eps) --------------------
    if (t < Cc) {
        float s2 = 0.f;
        for (int n = 0; n < Nn; ++n) { float kv_ = sC[n * Cc + t]; s2 += kv_ * kv_; }
        sKinv[t] = 1.0f / (EPSf + sqrtf(s2));
    }
    if (t == 128) {
        float s = 0.f;
        for (int n = 0; n < Nn; ++n) s += sMask[n];
        sInnum = 1.0f / (s + EPSf);
    }
    __syncthreads();

    // ---------------- kv[h][c][d] = kinv[c] * sum_n k3[n,c] * v[n,d] -----------------
    {
        const int h = t >> 5;
        const int r = t & 31;
        const int c = r & 15;
        const int dh = r >> 4;                       // 8 d's per thread
        const float* kp = sC + h * HDd + c;
        const float* vp = sA + h * HDd + dh * 8;
        float acc8[8];
        #pragma unroll
        for (int i = 0; i < 8; ++i) acc8[i] = 0.f;
        for (int n = 0; n < Nn; ++n) {
            float kval = kp[n * Cc];
            float vv[8];
            *(float4*)vv       = *(const float4*)(vp + n * Cc);
            *(float4*)(vv + 4) = *(const float4*)(vp + n * Cc + 4);
            #pragma unroll
            for (int i = 0; i < 8; ++i) acc8[i] += kval * vv[i];
        }
        float ki = sKinv[h * HDd + c];
        float* kvp = sKV + h * 260 + c * 16 + dh * 8;
        #pragma unroll
        for (int i = 0; i < 8; ++i) acc8[i] *= ki;
        *(float4*)kvp       = *(float4*)acc8;
        *(float4*)(kvp + 4) = *(float4*)(acc8 + 4);
    }
    __syncthreads();

    // ---------------- out[n][col] = (1/num) * sum_c qhat[n,c] kv[c,d] -> sC ----------
    {
        const int h = lane >> 3;                     // col = lane*2 -> head
        const int d0 = (lane * 2) & 15;
        const float inn = sInnum;
        const float* kvbase = sKV + h * 260 + d0;
        #pragma unroll 2
        for (int j = 0; j < 10; ++j) {
            int n = wv * 10 + j;
            float qa[16];
            const float* qp = sB + n * Cc + h * HDd;
            *(float4*)(qa)      = *(const float4*)(qp);
            *(float4*)(qa + 4)  = *(const float4*)(qp + 4);
            *(float4*)(qa + 8)  = *(const float4*)(qp + 8);
            *(float4*)(qa + 12) = *(const float4*)(qp + 12);
            float o0 = 0.f, o1 = 0.f;
            #pragma unroll
            for (int c = 0; c < 16; ++c) {
                float2 kv2 = *(const float2*)(kvbase + c * 16);
                o0 += qa[c] * kv2.x;
                o1 += qa[c] * kv2.y;
            }
            *(float2*)(sC + n * Cc + lane * 2) = make_float2(o0 * inn, o1 * inn);
        }
    }
    __syncthreads();

    // ---------------- proj GEMM + scatter by voxel_inds ------------------------------
    float accP[10][2];
    #pragma unroll
    for (int j = 0; j < 10; ++j) { accP[j][0] = 0.f; accP[j][1] = 0.f; }
    {
        const float* ap = sC + wv * 10 * Cc;
        const float* wp = proj_w + lane * 2;
        #pragma unroll 2
        for (int kk = 0; kk < Cc; kk += 4) {
            float a[10][4];
            #pragma unroll
            for (int j = 0; j < 10; ++j)
                *(float4*)a[j] = *(const float4*)(ap + j * Cc + kk);
            float w[4][2];
            #pragma unroll
            for (int i = 0; i < 4; ++i)
                *(float2*)w[i] = *(const float2*)(wp + (kk + i) * Cc);
            #pragma unroll
            for (int j = 0; j < 10; ++j) {
                #pragma unroll
                for (int ik = 0; ik < 4; ++ik) {
                    accP[j][0] += a[j][ik] * w[ik][0];
                    accP[j][1] += a[j][ik] * w[ik][1];
                }
            }
        }
    }
    {
        float pb0 = proj_b[lane * 2], pb1 = proj_b[lane * 2 + 1];
        #pragma unroll
        for (int j = 0; j < 10; ++j) {
            int n = wv * 10 + j;
            if (n < Nn) {
                int row = sVox[n];                   // out[vox[b,n]] = computed row (b,n)
                *(float2*)(out + (size_t)row * Cc + lane * 2) =
                    make_float2(accP[j][0] + pb0, accP[j][1] + pb1);
            }
        }
    }
}

extern "C" void kernel_launch(void* const* d_in, const int* in_sizes, int n_in,
                              void* d_out, int out_size, void* d_ws, size_t ws_size,
                              hipStream_t stream) {
    (void)in_sizes; (void)n_in; (void)out_size; (void)d_ws; (void)ws_size;
    const float* x      = (const float*)d_in[0];
    const float* pos    = (const float*)d_in[1];
    const float* mask   = (const float*)d_in[2];
    const float* qk_w   = (const float*)d_in[3];
    const float* qk_b   = (const float*)d_in[4];
    const float* v_w    = (const float*)d_in[5];
    const float* v_b    = (const float*)d_in[6];
    const float* proj_w = (const float*)d_in[7];
    const float* proj_b = (const float*)d_in[8];
    // d_in[9] = coords (unused; only its shape matters in the reference)
    const int*   vox    = (const int*)d_in[10];
    float* outp = (float*)d_out;

    hipLaunchKernelGGL(fla_fused, dim3(Bdim), dim3(256), 0, stream,
                       x, pos, mask, qk_w, qk_b, v_w, v_b, proj_w, proj_b, vox, outp);
}

// Round 2
// 461.248 us; speedup vs baseline: 1.4350x; 1.4350x over previous
//
#include <hip/hip_runtime.h>

typedef __bf16 bf16x8 __attribute__((ext_vector_type(8)));
typedef float f32x4 __attribute__((ext_vector_type(4)));

#define Bdim 8192
#define Nn 36
#define Cc 128
#define EPSf 1e-4f

// ---- d_ws layout (ushort elements); total 131072 ushorts = 256 KiB ----
#define WS_QK_HI 0
#define WS_QK_LO 32768
#define WS_V_HI  65536
#define WS_V_LO  81920
#define WS_P_HI  98304
#define WS_P_LO  114688

// ---- LDS byte offsets (single aliased arena) ----
#define OFF_XHI 0              // bf16 [48][128]  x hi        (phase A/B)
#define OFF_XLO 12288          // bf16 [48][128]  x lo
#define OFF_PHI 24576          // bf16 [48][128]  x+pos hi
#define OFF_PLO 36864          // bf16 [48][128]  x+pos lo
#define OFF_K   49152          // f32 [36][128]   k3hat       (phase C/D)
#define OFF_KV  67584          // f32 [8][260]    kv          (phase D/E)
#define OFF_MASK 75904         // f32 [48]
#define OFF_VOX  76096         // int [36]
#define OFF_INN  76240         // f32
#define LDS_BYTES 76288
// aliases (phase-disjoint):
#define OFF_V   0              // f32 [36][128]   v           (phase C/D, over XHI/XLO)
#define OFF_Q   24576          // f32 [36][128]   qhat        (phase C..E, over PHI/PLO)
#define OFF_OHI 0              // bf16 [48][128]  out hi      (phase E/G, over V)
#define OFF_OLO 12288          // bf16 [48][128]  out lo

__device__ inline uint bfh(float f) {
    __bf16 h = (__bf16)f;
    return (uint)(*(const ushort*)&h);
}
__device__ inline uint bfl(float f) {
    float hf = (float)((__bf16)f);
    __bf16 l = (__bf16)(f - hf);
    return (uint)(*(const ushort*)&l);
}

// ---------------- pre-kernel: weight -> frag-ordered bf16 hi/lo in ws ----------------
// frag element idx = ((ct*4 + ks)*64 + lane)*8 + j
// value = W[k][col], col = ct*16 + (lane&15), k = ks*32 + (lane>>4)*8 + j
__global__ __launch_bounds__(256)
void prep_frags(const float* __restrict__ qk_w, const float* __restrict__ v_w,
                const float* __restrict__ proj_w, ushort* __restrict__ ws)
{
    int e = blockIdx.x * 256 + threadIdx.x;          // 0..65535
    const float* W; int N; int hi_off; int lo_off; int idx;
    if (e < 32768)      { W = qk_w;   N = 256; hi_off = WS_QK_HI; lo_off = WS_QK_LO; idx = e; }
    else if (e < 49152) { W = v_w;    N = 128; hi_off = WS_V_HI;  lo_off = WS_V_LO;  idx = e - 32768; }
    else                { W = proj_w; N = 128; hi_off = WS_P_HI;  lo_off = WS_P_LO;  idx = e - 49152; }
    int j    = idx & 7;
    int lane = (idx >> 3) & 63;
    int ks   = (idx >> 9) & 3;
    int ct   = idx >> 11;
    int col  = ct * 16 + (lane & 15);
    int k    = ks * 32 + (lane >> 4) * 8 + j;
    float v  = W[k * N + col];
    ws[hi_off + idx] = (ushort)bfh(v);
    ws[lo_off + idx] = (ushort)bfl(v);
}

// ---------------- main fused kernel: one block (4 waves) per batch ----------------
__global__ __launch_bounds__(256, 2)
void fla_mfma(const float* __restrict__ x, const float* __restrict__ pos,
              const float* __restrict__ mask, const float* __restrict__ qk_b,
              const float* __restrict__ v_b, const float* __restrict__ proj_b,
              const int* __restrict__ vox, const ushort* __restrict__ ws,
              float* __restrict__ out)
{
    __shared__ __align__(16) char lds[LDS_BYTES];
    const int t = threadIdx.x;
    const int b = blockIdx.x;
    const int lane = t & 63;
    const int wv = t >> 6;

    const uint sw   = ((uint)lane & 7u) << 4;        // A-tile XOR swizzle (per-lane const)
    const uint rsel = (uint)lane & 15u;              // row-in-tile / col-in-tile
    const uint kgrp = ((uint)lane >> 4) * 8u;        // k sub-offset

    // ---------------- Phase A: stage x, x+pos as swizzled bf16 hi/lo ----------------
    const float* xg = x + (size_t)b * (Nn * Cc);
    const float* pg = pos + (size_t)b * (Nn * Cc);
    #pragma unroll
    for (int it = 0; it < 6; ++it) {
        int idx = t + it * 256;                       // 48 rows x 32 float4
        int n = idx >> 5;
        int c4 = (idx & 31) << 2;
        float4 xv = make_float4(0.f, 0.f, 0.f, 0.f);
        float4 pv = make_float4(0.f, 0.f, 0.f, 0.f);
        if (n < Nn) {
            xv = *(const float4*)(xg + n * Cc + c4);
            pv = *(const float4*)(pg + n * Cc + c4);
        }
        float p0 = xv.x + pv.x, p1 = xv.y + pv.y, p2 = xv.z + pv.z, p3 = xv.w + pv.w;
        uint ba = (uint)n * 256u + (((uint)(c4 * 2)) ^ (((uint)n & 7u) << 4));
        *(uint2*)(lds + OFF_XHI + ba) = make_uint2(bfh(xv.x) | (bfh(xv.y) << 16), bfh(xv.z) | (bfh(xv.w) << 16));
        *(uint2*)(lds + OFF_XLO + ba) = make_uint2(bfl(xv.x) | (bfl(xv.y) << 16), bfl(xv.z) | (bfl(xv.w) << 16));
        *(uint2*)(lds + OFF_PHI + ba) = make_uint2(bfh(p0) | (bfh(p1) << 16), bfh(p2) | (bfh(p3) << 16));
        *(uint2*)(lds + OFF_PLO + ba) = make_uint2(bfl(p0) | (bfl(p1) << 16), bfl(p2) | (bfl(p3) << 16));
    }
    if (t < 48) ((float*)(lds + OFF_MASK))[t] = (t < Nn) ? mask[(size_t)b * Nn + t] : 0.f;
    if (t >= 64 && t < 64 + Nn) ((int*)(lds + OFF_VOX))[t - 64] = vox[(size_t)b * Nn + (t - 64)];
    if (t == 128) {
        float s = 0.f;
        for (int n = 0; n < Nn; ++n) s += mask[(size_t)b * Nn + n];
        *(float*)(lds + OFF_INN) = 1.f / (s + EPSf);
    }
    __syncthreads();

    // ---------------- Phase B: v and qk GEMMs via split-bf16 MFMA ----------------
    f32x4 accV[3][2];
    f32x4 accQ[3][4];
    #pragma unroll
    for (int rt = 0; rt < 3; ++rt) {
        #pragma unroll
        for (int ci = 0; ci < 2; ++ci) accV[rt][ci] = (f32x4){0.f, 0.f, 0.f, 0.f};
        #pragma unroll
        for (int ci = 0; ci < 4; ++ci) accQ[rt][ci] = (f32x4){0.f, 0.f, 0.f, 0.f};
    }
    // v GEMM: A = x, B cols (wv*2+ci)*16
    #pragma unroll
    for (int ks = 0; ks < 4; ++ks) {
        uint ka = (((uint)(ks * 32) + kgrp) * 2u) ^ sw;
        bf16x8 ah[3], al[3];
        #pragma unroll
        for (int rt = 0; rt < 3; ++rt) {
            uint ba = (uint)(rt * 16 + (int)rsel) * 256u + ka;
            ah[rt] = *(const bf16x8*)(lds + OFF_XHI + ba);
            al[rt] = *(const bf16x8*)(lds + OFF_XLO + ba);
        }
        #pragma unroll
        for (int ci = 0; ci < 2; ++ci) {
            int f = (((wv * 2 + ci) * 4 + ks) * 64 + lane) * 8;
            bf16x8 bh = *(const bf16x8*)(ws + WS_V_HI + f);
            bf16x8 bl = *(const bf16x8*)(ws + WS_V_LO + f);
            #pragma unroll
            for (int rt = 0; rt < 3; ++rt) {
                accV[rt][ci] = __builtin_amdgcn_mfma_f32_16x16x32_bf16(ah[rt], bh, accV[rt][ci], 0, 0, 0);
                accV[rt][ci] = __builtin_amdgcn_mfma_f32_16x16x32_bf16(ah[rt], bl, accV[rt][ci], 0, 0, 0);
                accV[rt][ci] = __builtin_amdgcn_mfma_f32_16x16x32_bf16(al[rt], bh, accV[rt][ci], 0, 0, 0);
            }
        }
    }
    // qk GEMM: A = x+pos, B cols (wv*4+ci)*16 of 256
    #pragma unroll
    for (int ks = 0; ks < 4; ++ks) {
        uint ka = (((uint)(ks * 32) + kgrp) * 2u) ^ sw;
        bf16x8 ah[3], al[3];
        #pragma unroll
        for (int rt = 0; rt < 3; ++rt) {
            uint ba = (uint)(rt * 16 + (int)rsel) * 256u + ka;
            ah[rt] = *(const bf16x8*)(lds + OFF_PHI + ba);
            al[rt] = *(const bf16x8*)(lds + OFF_PLO + ba);
        }
        #pragma unroll
        for (int ci = 0; ci < 4; ++ci) {
            int f = (((wv * 4 + ci) * 4 + ks) * 64 + lane) * 8;
            bf16x8 bh = *(const bf16x8*)(ws + WS_QK_HI + f);
            bf16x8 bl = *(const bf16x8*)(ws + WS_QK_LO + f);
            #pragma unroll
            for (int rt = 0; rt < 3; ++rt) {
                accQ[rt][ci] = __builtin_amdgcn_mfma_f32_16x16x32_bf16(ah[rt], bh, accQ[rt][ci], 0, 0, 0);
                accQ[rt][ci] = __builtin_amdgcn_mfma_f32_16x16x32_bf16(ah[rt], bl, accQ[rt][ci], 0, 0, 0);
                accQ[rt][ci] = __builtin_amdgcn_mfma_f32_16x16x32_bf16(al[rt], bh, accQ[rt][ci], 0, 0, 0);
            }
        }
    }
    __syncthreads();   // staging reads done; aliased regions may be overwritten

    // ---------------- Phase C: epilogues -> sV, sQhat, sK ----------------
    float* sVf = (float*)(lds + OFF_V);
    float* sQf = (float*)(lds + OFF_Q);
    float* sKf = (float*)(lds + OFF_K);
    const float* sM = (const float*)(lds + OFF_MASK);
    {
        #pragma unroll
        for (int ci = 0; ci < 2; ++ci) {
            int col = (wv * 2 + ci) * 16 + (int)rsel;
            float vb = v_b[col];
            #pragma unroll
            for (int rt = 0; rt < 3; ++rt) {
                #pragma unroll
                for (int r = 0; r < 4; ++r) {
                    int row = rt * 16 + (lane >> 4) * 4 + r;
                    if (row < Nn) sVf[row * Cc + col] = accV[rt][ci][r] + vb;
                }
            }
        }
    }
    if (wv < 2) {      // q: +bias, cube, per-(row,head) norm
        #pragma unroll
        for (int ci = 0; ci < 4; ++ci) {
            int col = (wv * 4 + ci) * 16 + (int)rsel;
            float qb = qk_b[col];
            #pragma unroll
            for (int rt = 0; rt < 3; ++rt) {
                #pragma unroll
                for (int r = 0; r < 4; ++r) {
                    float q1 = accQ[rt][ci][r] + qb;
                    float q3 = q1 * q1 * q1;
                    float s2 = q3 * q3;
                    s2 += __shfl_xor(s2, 1);
                    s2 += __shfl_xor(s2, 2);
                    s2 += __shfl_xor(s2, 4);
                    s2 += __shfl_xor(s2, 8);
                    float qh = q3 / (EPSf + sqrtf(s2));
                    int row = rt * 16 + (lane >> 4) * 4 + r;
                    if (row < Nn) sQf[row * Cc + col] = qh;
                }
            }
        }
    } else {           // k: +bias, *mask, cube, per-column (over n) norm
        #pragma unroll
        for (int ci = 0; ci < 4; ++ci) {
            int kcol = ((wv - 2) * 4 + ci) * 16 + (int)rsel;
            float kb = qk_b[Cc + kcol];
            float k3v[3][4];
            float s2 = 0.f;
            #pragma unroll
            for (int rt = 0; rt < 3; ++rt) {
                #pragma unroll
                for (int r = 0; r < 4; ++r) {
                    int row = rt * 16 + (lane >> 4) * 4 + r;
                    float k1 = (accQ[rt][ci][r] + kb) * sM[row];
                    float k3 = k1 * k1 * k1;
                    k3v[rt][r] = k3;
                    s2 += k3 * k3;
                }
            }
            s2 += __shfl_xor(s2, 16);
            s2 += __shfl_xor(s2, 32);
            float inv = 1.f / (EPSf + sqrtf(s2));
            #pragma unroll
            for (int rt = 0; rt < 3; ++rt) {
                #pragma unroll
                for (int r = 0; r < 4; ++r) {
                    int row = rt * 16 + (lane >> 4) * 4 + r;
                    if (row < Nn) sKf[row * Cc + kcol] = k3v[rt][r] * inv;
                }
            }
        }
    }
    __syncthreads();

    // ---------------- Phase D: kv[h][c][d] = sum_n k3hat[n,c] * v[n,d] ----------------
    {
        int h = t >> 5, rr = t & 31, c = rr & 15, dh = rr >> 4;
        const float* kp = sKf + h * 16 + c;
        const float* vp = sVf + h * 16 + dh * 8;
        float a8[8];
        #pragma unroll
        for (int i = 0; i < 8; ++i) a8[i] = 0.f;
        for (int n = 0; n < Nn; ++n) {
            float kval = kp[n * Cc];
            float4 v0 = *(const float4*)(vp + n * Cc);
            float4 v1 = *(const float4*)(vp + n * Cc + 4);
            a8[0] += kval * v0.x; a8[1] += kval * v0.y; a8[2] += kval * v0.z; a8[3] += kval * v0.w;
            a8[4] += kval * v1.x; a8[5] += kval * v1.y; a8[6] += kval * v1.z; a8[7] += kval * v1.w;
        }
        float* kvp = (float*)(lds + OFF_KV) + h * 260 + c * 16 + dh * 8;
        *(float4*)kvp = make_float4(a8[0], a8[1], a8[2], a8[3]);
        *(float4*)(kvp + 4) = make_float4(a8[4], a8[5], a8[6], a8[7]);
    }
    __syncthreads();

    // ---------------- Phase E: out = (qhat @ kv)/num -> bf16 hi/lo (swizzled) --------
    {
        float inn = *(const float*)(lds + OFF_INN);
        int h = lane >> 3;
        int d0 = (lane * 2) & 15;
        const float* kvb = (const float*)(lds + OFF_KV) + h * 260 + d0;
        float kc0[16], kc1[16];
        #pragma unroll
        for (int c = 0; c < 16; ++c) {
            float2 kk = *(const float2*)(kvb + c * 16);
            kc0[c] = kk.x; kc1[c] = kk.y;
        }
        #pragma unroll
        for (int j = 0; j < 12; ++j) {
            int row = wv * 12 + j;
            uint ba = (uint)row * 256u + (((uint)(lane * 4)) ^ (((uint)row & 7u) << 4));
            uint oh = 0u, ol = 0u;
            if (row < Nn) {
                const float* qp = sQf + row * Cc + h * 16;
                float qa[16];
                *(float4*)(qa)      = *(const float4*)(qp);
                *(float4*)(qa + 4)  = *(const float4*)(qp + 4);
                *(float4*)(qa + 8)  = *(const float4*)(qp + 8);
                *(float4*)(qa + 12) = *(const float4*)(qp + 12);
                float o0 = 0.f, o1 = 0.f;
                #pragma unroll
                for (int c = 0; c < 16; ++c) { o0 += qa[c] * kc0[c]; o1 += qa[c] * kc1[c]; }
                o0 *= inn; o1 *= inn;
                oh = bfh(o0) | (bfh(o1) << 16);
                ol = bfl(o0) | (bfl(o1) << 16);
            }
            *(uint*)(lds + OFF_OHI + ba) = oh;
            *(uint*)(lds + OFF_OLO + ba) = ol;
        }
    }
    __syncthreads();

    // ---------------- Phase G: proj GEMM (split-bf16 MFMA) + scatter ----------------
    f32x4 accP[3][2];
    #pragma unroll
    for (int rt = 0; rt < 3; ++rt)
        #pragma unroll
        for (int ci = 0; ci < 2; ++ci) accP[rt][ci] = (f32x4){0.f, 0.f, 0.f, 0.f};
    #pragma unroll
    for (int ks = 0; ks < 4; ++ks) {
        uint ka = (((uint)(ks * 32) + kgrp) * 2u) ^ sw;
        bf16x8 ah[3], al[3];
        #pragma unroll
        for (int rt = 0; rt < 3; ++rt) {
            uint ba = (uint)(rt * 16 + (int)rsel) * 256u + ka;
            ah[rt] = *(const bf16x8*)(lds + OFF_OHI + ba);
            al[rt] = *(const bf16x8*)(lds + OFF_OLO + ba);
        }
        #pragma unroll
        for (int ci = 0; ci < 2; ++ci) {
            int f = (((wv * 2 + ci) * 4 + ks) * 64 + lane) * 8;
            bf16x8 bh = *(const bf16x8*)(ws + WS_P_HI + f);
            bf16x8 bl = *(const bf16x8*)(ws + WS_P_LO + f);
            #pragma unroll
            for (int rt = 0; rt < 3; ++rt) {
                accP[rt][ci] = __builtin_amdgcn_mfma_f32_16x16x32_bf16(ah[rt], bh, accP[rt][ci], 0, 0, 0);
                accP[rt][ci] = __builtin_amdgcn_mfma_f32_16x16x32_bf16(ah[rt], bl, accP[rt][ci], 0, 0, 0);
                accP[rt][ci] = __builtin_amdgcn_mfma_f32_16x16x32_bf16(al[rt], bh, accP[rt][ci], 0, 0, 0);
            }
        }
    }
    {
        const int* sVx = (const int*)(lds + OFF_VOX);
        #pragma unroll
        for (int ci = 0; ci < 2; ++ci) {
            int col = (wv * 2 + ci) * 16 + (int)rsel;
            float pb = proj_b[col];
            #pragma unroll
            for (int rt = 0; rt < 3; ++rt) {
                #pragma unroll
                for (int r = 0; r < 4; ++r) {
                    int row = rt * 16 + (lane >> 4) * 4 + r;
                    if (row < Nn)
                        out[(size_t)sVx[row] * Cc + col] = accP[rt][ci][r] + pb;
                }
            }
        }
    }
}

extern "C" void kernel_launch(void* const* d_in, const int* in_sizes, int n_in,
                              void* d_out, int out_size, void* d_ws, size_t ws_size,
                              hipStream_t stream) {
    (void)in_sizes; (void)n_in; (void)out_size; (void)ws_size;
    const float* x      = (const float*)d_in[0];
    const float* pos    = (const float*)d_in[1];
    const float* mask   = (const float*)d_in[2];
    const float* qk_w   = (const float*)d_in[3];
    const float* qk_b   = (const float*)d_in[4];
    const float* v_w    = (const float*)d_in[5];
    const float* v_b    = (const float*)d_in[6];
    const float* proj_w = (const float*)d_in[7];
    const float* proj_b = (const float*)d_in[8];
    // d_in[9] = coords (unused)
    const int*   vox    = (const int*)d_in[10];
    ushort* ws = (ushort*)d_ws;            // needs 256 KiB of scratch
    float* outp = (float*)d_out;

    hipLaunchKernelGGL(prep_frags, dim3(256), dim3(256), 0, stream, qk_w, v_w, proj_w, ws);
    hipLaunchKernelGGL(fla_mfma, dim3(Bdim), dim3(256), 0, stream,
                       x, pos, mask, qk_b, v_b, proj_b, vox, ws, outp);
}

// Round 3
// 319.895 us; speedup vs baseline: 2.0691x; 1.4419x over previous
//
#include <hip/hip_runtime.h>

typedef __bf16 bf16x8 __attribute__((ext_vector_type(8)));
typedef float f32x4 __attribute__((ext_vector_type(4)));

#define Bdim 8192
#define Nn 36
#define Cc 128
#define EPSf 1e-4f

// ---- d_ws layout (ushort elements); total 131072 ushorts = 256 KiB ----
#define WS_QK_HI 0
#define WS_QK_LO 32768
#define WS_V_HI  65536
#define WS_V_LO  81920
#define WS_P_HI  98304
#define WS_P_LO  114688

// ---- LDS byte offsets (single aliased arena) ----
#define OFF_XHI 0              // bf16 [48][128]  x hi         (A-B)
#define OFF_XLO 12288          // bf16 [48][128]  x lo         (A-B)
#define OFF_PHI 24576          // bf16 [48][128]  x+pos hi     (A-B)
#define OFF_PLO 36864          // bf16 [48][128]  x+pos lo     (A-B)
#define OFF_K   49152          // f32 [36][128]   k3hat        (C-D)
#define OFF_KV  67584          // f32 kv: h-stride 324, c-stride 20 (words)  (D-E)
#define OFF_MASK 77952         // f32 [48]
#define OFF_VOX  78144         // int [36]
#define OFF_INN  78288         // f32
#define LDS_BYTES 78336
// aliases (phase-disjoint):
#define OFF_V   0              // f32 [36][128]   v            (C-D, over XHI/XLO)
#define OFF_Q   24576          // f32 [36][128]   qhat         (C-E, over PHI/PLO)
#define OFF_OHI 0              // bf16 [48][128]  out hi       (E-G)
#define OFF_OLO 12288          // bf16 [48][128]  out lo       (E-G)

__device__ inline uint bfh(float f) {
    __bf16 h = (__bf16)f;
    return (uint)(*(const ushort*)&h);
}
__device__ inline uint bfl(float f) {
    float hf = (float)((__bf16)f);
    __bf16 l = (__bf16)(f - hf);
    return (uint)(*(const ushort*)&l);
}

// ---------------- pre-kernel: weight -> frag-ordered bf16 hi/lo in ws ----------------
// frag element idx = ((ct*4 + ks)*64 + lane)*8 + j
// value = W[k][col], col = ct*16 + (lane&15), k = ks*32 + (lane>>4)*8 + j
__global__ __launch_bounds__(256)
void prep_frags(const float* __restrict__ qk_w, const float* __restrict__ v_w,
                const float* __restrict__ proj_w, ushort* __restrict__ ws)
{
    int e = blockIdx.x * 256 + threadIdx.x;          // 0..65535
    const float* W; int N; int hi_off; int lo_off; int idx;
    if (e < 32768)      { W = qk_w;   N = 256; hi_off = WS_QK_HI; lo_off = WS_QK_LO; idx = e; }
    else if (e < 49152) { W = v_w;    N = 128; hi_off = WS_V_HI;  lo_off = WS_V_LO;  idx = e - 32768; }
    else                { W = proj_w; N = 128; hi_off = WS_P_HI;  lo_off = WS_P_LO;  idx = e - 49152; }
    int j    = idx & 7;
    int lane = (idx >> 3) & 63;
    int ks   = (idx >> 9) & 3;
    int ct   = idx >> 11;
    int col  = ct * 16 + (lane & 15);
    int k    = ks * 32 + (lane >> 4) * 8 + j;
    float v  = W[k * N + col];
    ws[hi_off + idx] = (ushort)bfh(v);
    ws[lo_off + idx] = (ushort)bfl(v);
}

// ---------------- main fused kernel: one block (8 waves, 512 thr) per batch ----------
__global__ __launch_bounds__(512, 4)
void fla_mfma(const float* __restrict__ x, const float* __restrict__ pos,
              const float* __restrict__ mask, const float* __restrict__ qk_b,
              const float* __restrict__ v_b, const float* __restrict__ proj_b,
              const int* __restrict__ vox, const ushort* __restrict__ ws,
              float* __restrict__ out)
{
    __shared__ __align__(16) char lds[LDS_BYTES];
    const int t = threadIdx.x;
    const int b = blockIdx.x;
    const int lane = t & 63;
    const int wv = t >> 6;                           // 8 waves

    const uint sw   = ((uint)lane & 7u) << 4;        // A-tile XOR swizzle
    const uint rsel = (uint)lane & 15u;
    const uint kgrp = ((uint)lane >> 4) * 8u;

    // ---------------- Phase A: stage x, x+pos as swizzled bf16 hi/lo ----------------
    const float* xg = x + (size_t)b * (Nn * Cc);
    const float* pg = pos + (size_t)b * (Nn * Cc);
    #pragma unroll
    for (int it = 0; it < 3; ++it) {
        int idx = t + it * 512;                       // 48 rows x 32 float4
        int n = idx >> 5;
        int c4 = (idx & 31) << 2;
        float4 xv = make_float4(0.f, 0.f, 0.f, 0.f);
        float4 pv = make_float4(0.f, 0.f, 0.f, 0.f);
        if (n < Nn) {
            xv = *(const float4*)(xg + n * Cc + c4);
            pv = *(const float4*)(pg + n * Cc + c4);
        }
        float p0 = xv.x + pv.x, p1 = xv.y + pv.y, p2 = xv.z + pv.z, p3 = xv.w + pv.w;
        uint ba = (uint)n * 256u + (((uint)(c4 * 2)) ^ (((uint)n & 7u) << 4));
        *(uint2*)(lds + OFF_XHI + ba) = make_uint2(bfh(xv.x) | (bfh(xv.y) << 16), bfh(xv.z) | (bfh(xv.w) << 16));
        *(uint2*)(lds + OFF_XLO + ba) = make_uint2(bfl(xv.x) | (bfl(xv.y) << 16), bfl(xv.z) | (bfl(xv.w) << 16));
        *(uint2*)(lds + OFF_PHI + ba) = make_uint2(bfh(p0) | (bfh(p1) << 16), bfh(p2) | (bfh(p3) << 16));
        *(uint2*)(lds + OFF_PLO + ba) = make_uint2(bfl(p0) | (bfl(p1) << 16), bfl(p2) | (bfl(p3) << 16));
    }
    if (t < 48) ((float*)(lds + OFF_MASK))[t] = (t < Nn) ? mask[(size_t)b * Nn + t] : 0.f;
    if (t >= 64 && t < 64 + Nn) ((int*)(lds + OFF_VOX))[t - 64] = vox[(size_t)b * Nn + (t - 64)];
    if (t == 128) {
        float s = 0.f;
        for (int n = 0; n < Nn; ++n) s += mask[(size_t)b * Nn + n];
        *(float*)(lds + OFF_INN) = 1.f / (s + EPSf);
    }
    __syncthreads();

    // ---------------- Phase B: v (1 tile/wave) and qk (2 tiles/wave) MFMA GEMMs ------
    f32x4 accV[3];
    f32x4 accQ[3][2];
    #pragma unroll
    for (int rt = 0; rt < 3; ++rt) {
        accV[rt] = (f32x4){0.f, 0.f, 0.f, 0.f};
        accQ[rt][0] = (f32x4){0.f, 0.f, 0.f, 0.f};
        accQ[rt][1] = (f32x4){0.f, 0.f, 0.f, 0.f};
    }
    #pragma unroll
    for (int ks = 0; ks < 4; ++ks) {
        uint ka = (((uint)(ks * 32) + kgrp) * 2u) ^ sw;
        bf16x8 ah[3], al[3];
        #pragma unroll
        for (int rt = 0; rt < 3; ++rt) {
            uint ba = (uint)(rt * 16 + (int)rsel) * 256u + ka;
            ah[rt] = *(const bf16x8*)(lds + OFF_XHI + ba);
            al[rt] = *(const bf16x8*)(lds + OFF_XLO + ba);
        }
        {
            int f = ((wv * 4 + ks) * 64 + lane) * 8;
            bf16x8 bh = *(const bf16x8*)(ws + WS_V_HI + f);
            bf16x8 bl = *(const bf16x8*)(ws + WS_V_LO + f);
            #pragma unroll
            for (int rt = 0; rt < 3; ++rt) {
                accV[rt] = __builtin_amdgcn_mfma_f32_16x16x32_bf16(ah[rt], bh, accV[rt], 0, 0, 0);
                accV[rt] = __builtin_amdgcn_mfma_f32_16x16x32_bf16(ah[rt], bl, accV[rt], 0, 0, 0);
                accV[rt] = __builtin_amdgcn_mfma_f32_16x16x32_bf16(al[rt], bh, accV[rt], 0, 0, 0);
            }
        }
    }
    #pragma unroll
    for (int ks = 0; ks < 4; ++ks) {
        uint ka = (((uint)(ks * 32) + kgrp) * 2u) ^ sw;
        bf16x8 ah[3], al[3];
        #pragma unroll
        for (int rt = 0; rt < 3; ++rt) {
            uint ba = (uint)(rt * 16 + (int)rsel) * 256u + ka;
            ah[rt] = *(const bf16x8*)(lds + OFF_PHI + ba);
            al[rt] = *(const bf16x8*)(lds + OFF_PLO + ba);
        }
        #pragma unroll
        for (int ci = 0; ci < 2; ++ci) {
            int f = (((wv * 2 + ci) * 4 + ks) * 64 + lane) * 8;
            bf16x8 bh = *(const bf16x8*)(ws + WS_QK_HI + f);
            bf16x8 bl = *(const bf16x8*)(ws + WS_QK_LO + f);
            #pragma unroll
            for (int rt = 0; rt < 3; ++rt) {
                accQ[rt][ci] = __builtin_amdgcn_mfma_f32_16x16x32_bf16(ah[rt], bh, accQ[rt][ci], 0, 0, 0);
                accQ[rt][ci] = __builtin_amdgcn_mfma_f32_16x16x32_bf16(ah[rt], bl, accQ[rt][ci], 0, 0, 0);
                accQ[rt][ci] = __builtin_amdgcn_mfma_f32_16x16x32_bf16(al[rt], bh, accQ[rt][ci], 0, 0, 0);
            }
        }
    }
    __syncthreads();   // staging reads done; aliased regions may be overwritten

    // ---------------- Phase C: epilogues -> sV, sQhat, sK ----------------
    float* sVf = (float*)(lds + OFF_V);
    float* sQf = (float*)(lds + OFF_Q);
    float* sKf = (float*)(lds + OFF_K);
    const float* sM = (const float*)(lds + OFF_MASK);
    {
        int col = wv * 16 + (int)rsel;
        float vb = v_b[col];
        #pragma unroll
        for (int rt = 0; rt < 3; ++rt) {
            #pragma unroll
            for (int r = 0; r < 4; ++r) {
                int row = rt * 16 + (lane >> 4) * 4 + r;
                if (row < Nn) sVf[row * Cc + col] = accV[rt][r] + vb;
            }
        }
    }
    if (wv < 4) {      // q: +bias, cube, per-(row,head) norm
        #pragma unroll
        for (int ci = 0; ci < 2; ++ci) {
            int col = (wv * 2 + ci) * 16 + (int)rsel;
            float qb = qk_b[col];
            #pragma unroll
            for (int rt = 0; rt < 3; ++rt) {
                #pragma unroll
                for (int r = 0; r < 4; ++r) {
                    float q1 = accQ[rt][ci][r] + qb;
                    float q3 = q1 * q1 * q1;
                    float s2 = q3 * q3;
                    s2 += __shfl_xor(s2, 1);
                    s2 += __shfl_xor(s2, 2);
                    s2 += __shfl_xor(s2, 4);
                    s2 += __shfl_xor(s2, 8);
                    float qh = q3 / (EPSf + sqrtf(s2));
                    int row = rt * 16 + (lane >> 4) * 4 + r;
                    if (row < Nn) sQf[row * Cc + col] = qh;
                }
            }
        }
    } else {           // k: +bias, *mask, cube, per-column (over n) norm
        #pragma unroll
        for (int ci = 0; ci < 2; ++ci) {
            int kcol = ((wv - 4) * 2 + ci) * 16 + (int)rsel;
            float kb = qk_b[Cc + kcol];
            float k3v[3][4];
            float s2 = 0.f;
            #pragma unroll
            for (int rt = 0; rt < 3; ++rt) {
                #pragma unroll
                for (int r = 0; r < 4; ++r) {
                    int row = rt * 16 + (lane >> 4) * 4 + r;
                    float k1 = (accQ[rt][ci][r] + kb) * sM[row];
                    float k3 = k1 * k1 * k1;
                    k3v[rt][r] = k3;
                    s2 += k3 * k3;
                }
            }
            s2 += __shfl_xor(s2, 16);
            s2 += __shfl_xor(s2, 32);
            float inv = 1.f / (EPSf + sqrtf(s2));
            #pragma unroll
            for (int rt = 0; rt < 3; ++rt) {
                #pragma unroll
                for (int r = 0; r < 4; ++r) {
                    int row = rt * 16 + (lane >> 4) * 4 + r;
                    if (row < Nn) sKf[row * Cc + kcol] = k3v[rt][r] * inv;
                }
            }
        }
    }
    __syncthreads();

    // ---------------- Phase D: kv[h][c][d] = sum_n k3hat[n,c] * v[n,d] ---------------
    // h = wv; thread owns (c = lane&15, d = (lane>>4)*4 .. +3)
    {
        int c = lane & 15, dq = (lane >> 4) * 4;
        const float* kp = sKf + wv * 16 + c;
        const float* vp = sVf + wv * 16 + dq;
        f32x4 a4 = (f32x4){0.f, 0.f, 0.f, 0.f};
        for (int n = 0; n < Nn; ++n) {
            float kval = kp[n * Cc];
            float4 v4 = *(const float4*)(vp + n * Cc);
            a4[0] += kval * v4.x; a4[1] += kval * v4.y;
            a4[2] += kval * v4.z; a4[3] += kval * v4.w;
        }
        float* kvp = (float*)(lds + OFF_KV) + wv * 324 + c * 20 + dq;
        *(f32x4*)kvp = a4;
    }
    __syncthreads();

    // ---------------- Phase E: out = (qhat @ kv)/num -> bf16 hi/lo (swizzled) --------
    {
        float inn = *(const float*)(lds + OFF_INN);
        int h = lane >> 3;
        int d0 = (lane * 2) & 15;
        const float* kvb = (const float*)(lds + OFF_KV) + h * 324 + d0;
        float kc0[16], kc1[16];
        #pragma unroll
        for (int c = 0; c < 16; ++c) {
            float2 kk = *(const float2*)(kvb + c * 20);
            kc0[c] = kk.x; kc1[c] = kk.y;
        }
        #pragma unroll
        for (int j = 0; j < 6; ++j) {
            int row = wv * 6 + j;
            uint ba = (uint)row * 256u + (((uint)(lane * 4)) ^ (((uint)row & 7u) << 4));
            uint oh = 0u, ol = 0u;
            if (row < Nn) {
                const float* qp = sQf + row * Cc + h * 16;
                float qa[16];
                *(float4*)(qa)      = *(const float4*)(qp);
                *(float4*)(qa + 4)  = *(const float4*)(qp + 4);
                *(float4*)(qa + 8)  = *(const float4*)(qp + 8);
                *(float4*)(qa + 12) = *(const float4*)(qp + 12);
                float o0 = 0.f, o1 = 0.f;
                #pragma unroll
                for (int c = 0; c < 16; ++c) { o0 += qa[c] * kc0[c]; o1 += qa[c] * kc1[c]; }
                o0 *= inn; o1 *= inn;
                oh = bfh(o0) | (bfh(o1) << 16);
                ol = bfl(o0) | (bfl(o1) << 16);
            }
            *(uint*)(lds + OFF_OHI + ba) = oh;
            *(uint*)(lds + OFF_OLO + ba) = ol;
        }
    }
    __syncthreads();

    // ---------------- Phase G: proj GEMM (1 tile/wave) + scatter ---------------------
    f32x4 accP[3];
    #pragma unroll
    for (int rt = 0; rt < 3; ++rt) accP[rt] = (f32x4){0.f, 0.f, 0.f, 0.f};
    #pragma unroll
    for (int ks = 0; ks < 4; ++ks) {
        uint ka = (((uint)(ks * 32) + kgrp) * 2u) ^ sw;
        bf16x8 ah[3], al[3];
        #pragma unroll
        for (int rt = 0; rt < 3; ++rt) {
            uint ba = (uint)(rt * 16 + (int)rsel) * 256u + ka;
            ah[rt] = *(const bf16x8*)(lds + OFF_OHI + ba);
            al[rt] = *(const bf16x8*)(lds + OFF_OLO + ba);
        }
        {
            int f = ((wv * 4 + ks) * 64 + lane) * 8;
            bf16x8 bh = *(const bf16x8*)(ws + WS_P_HI + f);
            bf16x8 bl = *(const bf16x8*)(ws + WS_P_LO + f);
            #pragma unroll
            for (int rt = 0; rt < 3; ++rt) {
                accP[rt] = __builtin_amdgcn_mfma_f32_16x16x32_bf16(ah[rt], bh, accP[rt], 0, 0, 0);
                accP[rt] = __builtin_amdgcn_mfma_f32_16x16x32_bf16(ah[rt], bl, accP[rt], 0, 0, 0);
                accP[rt] = __builtin_amdgcn_mfma_f32_16x16x32_bf16(al[rt], bh, accP[rt], 0, 0, 0);
            }
        }
    }
    {
        const int* sVx = (const int*)(lds + OFF_VOX);
        int col = wv * 16 + (int)rsel;
        float pb = proj_b[col];
        #pragma unroll
        for (int rt = 0; rt < 3; ++rt) {
            #pragma unroll
            for (int r = 0; r < 4; ++r) {
                int row = rt * 16 + (lane >> 4) * 4 + r;
                if (row < Nn)
                    out[(size_t)sVx[row] * Cc + col] = accP[rt][r] + pb;
            }
        }
    }
}

extern "C" void kernel_launch(void* const* d_in, const int* in_sizes, int n_in,
                              void* d_out, int out_size, void* d_ws, size_t ws_size,
                              hipStream_t stream) {
    (void)in_sizes; (void)n_in; (void)out_size; (void)ws_size;
    const float* x      = (const float*)d_in[0];
    const float* pos    = (const float*)d_in[1];
    const float* mask   = (const float*)d_in[2];
    const float* qk_w   = (const float*)d_in[3];
    const float* qk_b   = (const float*)d_in[4];
    const float* v_w    = (const float*)d_in[5];
    const float* v_b    = (const float*)d_in[6];
    const float* proj_w = (const float*)d_in[7];
    const float* proj_b = (const float*)d_in[8];
    // d_in[9] = coords (unused)
    const int*   vox    = (const int*)d_in[10];
    ushort* ws = (ushort*)d_ws;            // 256 KiB scratch
    float* outp = (float*)d_out;

    hipLaunchKernelGGL(prep_frags, dim3(256), dim3(256), 0, stream, qk_w, v_w, proj_w, ws);
    hipLaunchKernelGGL(fla_mfma, dim3(Bdim), dim3(512), 0, stream,
                       x, pos, mask, qk_b, v_b, proj_b, vox, ws, outp);
}

// Round 4
// 222.326 us; speedup vs baseline: 2.9771x; 1.4389x over previous
//
#include <hip/hip_runtime.h>

typedef __bf16 bf16x8 __attribute__((ext_vector_type(8)));
typedef float f32x4 __attribute__((ext_vector_type(4)));

#define Bdim 8192
#define Nn 36
#define Cc 128
#define EPSf 1e-4f

// ---- d_ws layout (ushort elements): qk hi/lo split, v/proj single-bf16 ----
#define WS_QK_HI 0
#define WS_QK_LO 32768
#define WS_V_HI  65536
#define WS_P_HI  81920
// total 98304 ushorts = 192 KiB

// ---- LDS arena (byte offsets); lifetimes allow aliasing ----
#define OFF_XH   0        // ush [48][128] swz  x hi          (A->B)
#define OFF_PH   12288    // ush [48][128] swz  x+pos hi      (A->B)
#define OFF_PL   24576    // ush [48][128] swz  x+pos lo      (A->B)
#define OFF_KT   0        // ush [128 c][56 n]  raw k3 bf16   (C->D) over XH
#define OFF_VT   14336    // ush [128 d][56 n]  v bf16        (C->D)
#define OFF_KV   28672    // f32 [8][16 c][20 d] kv-hat       (D->E)
#define OFF_QH   38912    // ush [48][128] swz  raw q3 bf16   (C->E)
#define OFF_O    0        // ush [48][128] swz  attn out bf16 (E->G) over KT
#define OFF_MASK 51200    // f32 [48]
#define OFF_VOX  51392    // int [48]
#define OFF_INN  51584    // f32
#define LDS_BYTES 51712

__device__ inline uint bfh(float f) {
    __bf16 h = (__bf16)f;
    return (uint)(*(const ushort*)&h);
}
__device__ inline uint bfl(float f) {
    float hf = (float)((__bf16)f);
    __bf16 l = (__bf16)(f - hf);
    return (uint)(*(const ushort*)&l);
}
__device__ inline uint pk2h(float a, float b) { return bfh(a) | (bfh(b) << 16); }
__device__ inline uint pk2l(float a, float b) { return bfl(a) | (bfl(b) << 16); }

union U8 { bf16x8 v; uint u[4]; };

// ---------------- pre-kernel: weights -> frag-ordered bf16 in ws ----------------
// frag element idx = ((ct*4 + ks)*64 + lane)*8 + j
// value = W[k][col], col = ct*16 + (lane&15), k = ks*32 + (lane>>4)*8 + j
__global__ __launch_bounds__(256)
void prep_frags(const float* __restrict__ qk_w, const float* __restrict__ v_w,
                const float* __restrict__ proj_w, ushort* __restrict__ ws)
{
    int e = blockIdx.x * 256 + threadIdx.x;          // 0..65535
    const float* W; int N; int idx; int hi_off; int lo_off;
    if (e < 32768)      { W = qk_w;   N = 256; hi_off = WS_QK_HI; lo_off = WS_QK_LO; idx = e; }
    else if (e < 49152) { W = v_w;    N = 128; hi_off = WS_V_HI;  lo_off = -1;       idx = e - 32768; }
    else                { W = proj_w; N = 128; hi_off = WS_P_HI;  lo_off = -1;       idx = e - 49152; }
    int j    = idx & 7;
    int lane = (idx >> 3) & 63;
    int ks   = (idx >> 9) & 3;
    int ct   = idx >> 11;
    int col  = ct * 16 + (lane & 15);
    int k    = ks * 32 + (lane >> 4) * 8 + j;
    float v  = W[k * N + col];
    ws[hi_off + idx] = (ushort)bfh(v);
    if (lo_off >= 0) ws[lo_off + idx] = (ushort)bfl(v);
}

// ---------------- main fused kernel: one block (8 waves) per batch ----------------
__global__ __launch_bounds__(512, 6)
void fla_mfma(const float* __restrict__ x, const float* __restrict__ pos,
              const float* __restrict__ mask, const float* __restrict__ qk_b,
              const float* __restrict__ v_b, const float* __restrict__ proj_b,
              const int* __restrict__ vox, const ushort* __restrict__ ws,
              float* __restrict__ out)
{
    __shared__ __align__(16) char lds[LDS_BYTES];
    const int t = threadIdx.x;
    const int b = blockIdx.x;
    const int lane = t & 63;
    const int wv = t >> 6;                           // 8 waves

    const uint sw   = ((uint)lane & 7u) << 4;        // row-XOR swizzle for A-frag reads
    const int  rsel = lane & 15;
    const int  grp  = lane >> 4;
    const uint kgrp = (uint)grp * 8u;

    // ---------------- Phase A: stage x(hi), (x+pos)(hi,lo) swizzled ----------------
    const float* xg = x + (size_t)b * (Nn * Cc);
    const float* pg = pos + (size_t)b * (Nn * Cc);
    #pragma unroll
    for (int it = 0; it < 3; ++it) {
        int idx = t + it * 512;                       // 48 rows x 32 float4
        int n = idx >> 5;
        int c4 = (idx & 31) << 2;
        float4 xv = make_float4(0.f, 0.f, 0.f, 0.f);
        float4 pv = make_float4(0.f, 0.f, 0.f, 0.f);
        if (n < Nn) {
            xv = *(const float4*)(xg + n * Cc + c4);
            pv = *(const float4*)(pg + n * Cc + c4);
        }
        float s0 = xv.x + pv.x, s1 = xv.y + pv.y, s2 = xv.z + pv.z, s3 = xv.w + pv.w;
        uint ba = (uint)n * 256u + (((uint)(c4 * 2)) ^ (((uint)n & 7u) << 4));
        *(uint2*)(lds + OFF_XH + ba) = make_uint2(pk2h(xv.x, xv.y), pk2h(xv.z, xv.w));
        *(uint2*)(lds + OFF_PH + ba) = make_uint2(pk2h(s0, s1), pk2h(s2, s3));
        *(uint2*)(lds + OFF_PL + ba) = make_uint2(pk2l(s0, s1), pk2l(s2, s3));
    }
    if (t < 48) ((float*)(lds + OFF_MASK))[t] = (t < Nn) ? mask[(size_t)b * Nn + t] : 0.f;
    if (t >= 64 && t < 64 + Nn) ((int*)(lds + OFF_VOX))[t - 64] = vox[(size_t)b * Nn + (t - 64)];
    if (t == 128) {
        float s = 0.f;
        for (int n = 0; n < Nn; ++n) s += mask[(size_t)b * Nn + n];
        *(float*)(lds + OFF_INN) = 1.f / (s + EPSf);
    }
    __syncthreads();

    // ---------------- Phase B: v GEMM (single-bf16) + qk GEMM (split-bf16) ----------
    f32x4 accV[3];
    f32x4 accQ[3][2];
    #pragma unroll
    for (int rt = 0; rt < 3; ++rt) {
        accV[rt] = (f32x4){0.f, 0.f, 0.f, 0.f};
        accQ[rt][0] = (f32x4){0.f, 0.f, 0.f, 0.f};
        accQ[rt][1] = (f32x4){0.f, 0.f, 0.f, 0.f};
    }
    #pragma unroll
    for (int ks = 0; ks < 4; ++ks) {                  // v: A = x(hi) only
        uint ka = (((uint)(ks * 32) + kgrp) * 2u) ^ sw;
        bf16x8 xh[3];
        #pragma unroll
        for (int rt = 0; rt < 3; ++rt)
            xh[rt] = *(const bf16x8*)(lds + OFF_XH + (uint)(rt * 16 + rsel) * 256u + ka);
        int f = ((wv * 4 + ks) * 64 + lane) * 8;
        bf16x8 bvh = *(const bf16x8*)(ws + WS_V_HI + f);
        #pragma unroll
        for (int rt = 0; rt < 3; ++rt)
            accV[rt] = __builtin_amdgcn_mfma_f32_16x16x32_bf16(xh[rt], bvh, accV[rt], 0, 0, 0);
    }
    #pragma unroll
    for (int ks = 0; ks < 4; ++ks) {                  // qk: split 3-product
        uint ka = (((uint)(ks * 32) + kgrp) * 2u) ^ sw;
        bf16x8 ph[3], pl[3];
        #pragma unroll
        for (int rt = 0; rt < 3; ++rt) {
            uint ba = (uint)(rt * 16 + rsel) * 256u + ka;
            ph[rt] = *(const bf16x8*)(lds + OFF_PH + ba);
            pl[rt] = *(const bf16x8*)(lds + OFF_PL + ba);
        }
        #pragma unroll
        for (int ci = 0; ci < 2; ++ci) {
            int f = (((wv * 2 + ci) * 4 + ks) * 64 + lane) * 8;
            bf16x8 bh = *(const bf16x8*)(ws + WS_QK_HI + f);
            bf16x8 bl = *(const bf16x8*)(ws + WS_QK_LO + f);
            #pragma unroll
            for (int rt = 0; rt < 3; ++rt) {
                accQ[rt][ci] = __builtin_amdgcn_mfma_f32_16x16x32_bf16(ph[rt], bh, accQ[rt][ci], 0, 0, 0);
                accQ[rt][ci] = __builtin_amdgcn_mfma_f32_16x16x32_bf16(ph[rt], bl, accQ[rt][ci], 0, 0, 0);
                accQ[rt][ci] = __builtin_amdgcn_mfma_f32_16x16x32_bf16(pl[rt], bh, accQ[rt][ci], 0, 0, 0);
            }
        }
    }
    __syncthreads();   // staging dead; C may overwrite

    // ---------------- Phase C: epilogues -> Vt, QH(raw q3), KT(raw k3) --------------
    const float* sM = (const float*)(lds + OFF_MASK);
    {   // v: +bias -> bf16 -> Vt[d=col][n], b64 per row-group
        int colv = wv * 16 + rsel;
        float vb = v_b[colv];
        #pragma unroll
        for (int rt = 0; rt < 3; ++rt) {
            float a0 = accV[rt][0] + vb, a1 = accV[rt][1] + vb;
            float a2 = accV[rt][2] + vb, a3 = accV[rt][3] + vb;
            uint addr = OFF_VT + (uint)(colv * 56 + rt * 16 + grp * 4) * 2u;
            *(uint2*)(lds + addr) = make_uint2(pk2h(a0, a1), pk2h(a2, a3));
        }
    }
    if (wv < 4) {       // q: +bias, cube (raw, norm deferred to E) -> QH scatter
        #pragma unroll
        for (int ci = 0; ci < 2; ++ci) {
            int colq = (wv * 2 + ci) * 16 + rsel;
            float qb = qk_b[colq];
            uint cb2 = (uint)(colq * 2);
            #pragma unroll
            for (int rt = 0; rt < 3; ++rt) {
                #pragma unroll
                for (int r = 0; r < 4; ++r) {
                    int row = rt * 16 + grp * 4 + r;
                    float q1 = accQ[rt][ci][r] + qb;
                    float q3 = q1 * q1 * q1;
                    uint ba = (uint)row * 256u + (cb2 ^ (((uint)row & 7u) << 4));
                    *(ushort*)(lds + OFF_QH + ba) = (ushort)bfh(q3);
                }
            }
        }
    } else {            // k: +bias, *mask, cube (raw) -> KT[c=col][n], b64
        #pragma unroll
        for (int ci = 0; ci < 2; ++ci) {
            int colk = ((wv - 4) * 2 + ci) * 16 + rsel;
            float kb = qk_b[Cc + colk];
            #pragma unroll
            for (int rt = 0; rt < 3; ++rt) {
                float k3v[4];
                #pragma unroll
                for (int r = 0; r < 4; ++r) {
                    int row = rt * 16 + grp * 4 + r;
                    float k1 = (accQ[rt][ci][r] + kb) * sM[row];
                    k3v[r] = k1 * k1 * k1;
                }
                uint addr = OFF_KT + (uint)(colk * 56 + rt * 16 + grp * 4) * 2u;
                *(uint2*)(lds + addr) = make_uint2(pk2h(k3v[0], k3v[1]), pk2h(k3v[2], k3v[3]));
            }
        }
    }
    __syncthreads();

    // ---------------- Phase D: kv-hat = invkn[c] * (k3^T @ v) via MFMA ---------------
    {
        int c16 = rsel;                   // A-row (c) and B-col (d) index
        int col16 = wv * 16 + c16;
        uint a0 = OFF_KT + (uint)(col16 * 56 + grp * 8) * 2u;
        uint b0 = OFF_VT + (uint)(col16 * 56 + grp * 8) * 2u;
        bf16x8 kA0 = *(const bf16x8*)(lds + a0);
        bf16x8 vB0 = *(const bf16x8*)(lds + b0);
        U8 kA1, vB1;
        kA1.u[0] = kA1.u[1] = kA1.u[2] = kA1.u[3] = 0u;
        vB1.u[0] = vB1.u[1] = vB1.u[2] = vB1.u[3] = 0u;
        if (grp < 2) {                    // n = 32 + grp*8 .. +7 (n>=48 stays zero)
            kA1.v = *(const bf16x8*)(lds + a0 + 64);
            vB1.v = *(const bf16x8*)(lds + b0 + 64);
        }
        // column norm of raw k3 (from the same bf16 values the MFMA consumes)
        float s = 0.f;
        #pragma unroll
        for (int j = 0; j < 8; ++j) { float q = (float)kA0[j]; s += q * q; }
        #pragma unroll
        for (int j = 0; j < 8; ++j) { float q = (float)kA1.v[j]; s += q * q; }
        s += __shfl_xor(s, 16);
        s += __shfl_xor(s, 32);
        float invkn = 1.f / (EPSf + sqrtf(s));

        f32x4 kvacc = (f32x4){0.f, 0.f, 0.f, 0.f};
        kvacc = __builtin_amdgcn_mfma_f32_16x16x32_bf16(kA0, vB0, kvacc, 0, 0, 0);
        kvacc = __builtin_amdgcn_mfma_f32_16x16x32_bf16(kA1.v, vB1.v, kvacc, 0, 0, 0);

        float* kvp = (float*)(lds + OFF_KV) + wv * 320;
        #pragma unroll
        for (int r = 0; r < 4; ++r) {
            int c_out = grp * 4 + r;
            float fac = __shfl(invkn, c_out);          // invkn lives at lane c_out
            kvp[c_out * 20 + c16] = kvacc[r] * fac;    // kv[c_out][d=c16]
        }
    }
    __syncthreads();

    // ---------------- Phase E: out = invn[row]*inn * (q3 @ kv-hat) via MFMA ----------
    {
        int d = rsel;
        float inn = *(const float*)(lds + OFF_INN);
        U8 bkv;
        bkv.u[0] = bkv.u[1] = bkv.u[2] = bkv.u[3] = 0u;
        if (grp < 2) {                      // c = grp*8 + j
            const float* kvp = (const float*)(lds + OFF_KV) + wv * 320 + (grp * 8) * 20 + d;
            float f0 = kvp[0],  f1 = kvp[20], f2 = kvp[40],  f3 = kvp[60];
            float f4 = kvp[80], f5 = kvp[100], f6 = kvp[120], f7 = kvp[140];
            bkv.u[0] = pk2h(f0, f1); bkv.u[1] = pk2h(f2, f3);
            bkv.u[2] = pk2h(f4, f5); bkv.u[3] = pk2h(f6, f7);
        }
        f32x4 oacc[3];
        float invn[3];
        #pragma unroll
        for (int rt = 0; rt < 3; ++rt) {
            int row = rt * 16 + rsel;
            U8 aq;
            aq.u[0] = aq.u[1] = aq.u[2] = aq.u[3] = 0u;
            if (grp < 2) {
                uint ba = (uint)row * 256u +
                          (((uint)((wv * 16 + grp * 8) * 2)) ^ (((uint)row & 7u) << 4));
                aq.v = *(const bf16x8*)(lds + OFF_QH + ba);
            }
            float s = 0.f;
            #pragma unroll
            for (int j = 0; j < 8; ++j) { float q = (float)aq.v[j]; s += q * q; }
            s += __shfl_xor(s, 16);                     // row-norm2 (valid on lanes<32)
            invn[rt] = 1.f / (EPSf + sqrtf(s));
            f32x4 o = (f32x4){0.f, 0.f, 0.f, 0.f};
            o = __builtin_amdgcn_mfma_f32_16x16x32_bf16(aq.v, bkv.v, o, 0, 0, 0);
            oacc[rt] = o;
        }
        #pragma unroll
        for (int rt = 0; rt < 3; ++rt) {
            #pragma unroll
            for (int r = 0; r < 4; ++r) {
                int rr = grp * 4 + r;
                int row = rt * 16 + rr;
                float fac = __shfl(invn[rt], rr) * inn;
                float val = oacc[rt][r] * fac;
                uint ba = (uint)row * 256u +
                          (((uint)((wv * 16 + d) * 2)) ^ (((uint)row & 7u) << 4));
                *(ushort*)(lds + OFF_O + ba) = (ushort)bfh(val);
            }
        }
    }
    __syncthreads();

    // ---------------- Phase G: proj GEMM (single-bf16) + scatter ---------------------
    f32x4 accP[3];
    #pragma unroll
    for (int rt = 0; rt < 3; ++rt) accP[rt] = (f32x4){0.f, 0.f, 0.f, 0.f};
    #pragma unroll
    for (int ks = 0; ks < 4; ++ks) {
        uint ka = (((uint)(ks * 32) + kgrp) * 2u) ^ sw;
        bf16x8 oa[3];
        #pragma unroll
        for (int rt = 0; rt < 3; ++rt)
            oa[rt] = *(const bf16x8*)(lds + OFF_O + (uint)(rt * 16 + rsel) * 256u + ka);
        int f = ((wv * 4 + ks) * 64 + lane) * 8;
        bf16x8 bp = *(const bf16x8*)(ws + WS_P_HI + f);
        #pragma unroll
        for (int rt = 0; rt < 3; ++rt)
            accP[rt] = __builtin_amdgcn_mfma_f32_16x16x32_bf16(oa[rt], bp, accP[rt], 0, 0, 0);
    }
    {
        const int* sVx = (const int*)(lds + OFF_VOX);
        int col = wv * 16 + rsel;
        float pb = proj_b[col];
        #pragma unroll
        for (int rt = 0; rt < 3; ++rt) {
            #pragma unroll
            for (int r = 0; r < 4; ++r) {
                int row = rt * 16 + grp * 4 + r;
                if (row < Nn)
                    out[(size_t)sVx[row] * Cc + col] = accP[rt][r] + pb;
            }
        }
    }
}

extern "C" void kernel_launch(void* const* d_in, const int* in_sizes, int n_in,
                              void* d_out, int out_size, void* d_ws, size_t ws_size,
                              hipStream_t stream) {
    (void)in_sizes; (void)n_in; (void)out_size; (void)ws_size;
    const float* x      = (const float*)d_in[0];
    const float* pos    = (const float*)d_in[1];
    const float* mask   = (const float*)d_in[2];
    const float* qk_w   = (const float*)d_in[3];
    const float* qk_b   = (const float*)d_in[4];
    const float* v_w    = (const float*)d_in[5];
    const float* v_b    = (const float*)d_in[6];
    const float* proj_w = (const float*)d_in[7];
    const float* proj_b = (const float*)d_in[8];
    // d_in[9] = coords (unused)
    const int*   vox    = (const int*)d_in[10];
    ushort* ws = (ushort*)d_ws;            // 192 KiB scratch used
    float* outp = (float*)d_out;

    hipLaunchKernelGGL(prep_frags, dim3(256), dim3(256), 0, stream, qk_w, v_w, proj_w, ws);
    hipLaunchKernelGGL(fla_mfma, dim3(Bdim), dim3(512), 0, stream,
                       x, pos, mask, qk_b, v_b, proj_b, vox, ws, outp);
}